// Round 6
// baseline (798.861 us; speedup 1.0000x reference)
//
#include <hip/hip_runtime.h>
#include <hip/hip_bf16.h>
#include <stdint.h>

#define NN 50000
#define NE 1600000
#define BE 32

typedef __attribute__((ext_vector_type(8))) short short8;
typedef __attribute__((ext_vector_type(4))) float f32x4;

__device__ __forceinline__ unsigned short f2bf(float f) {
    unsigned int u = __float_as_uint(f);
    u += 0x7fff + ((u >> 16) & 1);   // round-nearest-even
    return (unsigned short)(u >> 16);
}

// packed 2x f32 -> 2x bf16 (v_cvt_pk_bf16_f32 on gfx950)
__device__ __forceinline__ unsigned int pk2bf(float lo, float hi) {
    __hip_bfloat162 b = __float22bfloat162_rn(float2{lo, hi});
    return *(unsigned int*)&b;
}

// silu via fast rcp (v_rcp_f32) instead of precise divide
__device__ __forceinline__ float silu_f(float v) {
    return v * __builtin_amdgcn_rcpf(1.0f + __expf(-v));
}

// ws layout (bytes):
// [0, 98304)            bf16 weights: node_w1^T [128][160] | coord_w1^T [128][160] | node_w2^T [64][128]
// [98304, 100352)       ew2^T bf16 [32 out][32 k]
// [100352, 6500352)     h_bf16 [50000][64]          (optional, ws_size-gated)
// [6500352, 7300352)    x4 float4 [50000]           (optional, ws_size-gated)
#define WS_EW2T_US   49152          // ushort offset of ew2T
#define WS_HB_B      100352
#define WS_XP_B      6500352
#define WS_HB_NEED   6500352
#define WS_XP_NEED   7300352

__global__ void prep_kernel(const float* __restrict__ nw1,
                            const float* __restrict__ cw1,
                            const float* __restrict__ nw2,
                            const float* __restrict__ ew2,
                            unsigned short* __restrict__ ws) {
    int i = blockIdx.x * 256 + threadIdx.x;
    if (i < 20480) {
        int n = i / 160, k = i % 160;
        ws[i] = f2bf(nw1[k * 128 + n]);
    } else if (i < 40960) {
        int j = i - 20480; int n = j / 160, k = j % 160;
        ws[i] = f2bf(cw1[k * 128 + n]);
    } else if (i < 49152) {
        int j = i - 40960; int o = j / 128, k = j % 128;
        ws[i] = f2bf(nw2[k * 64 + o]);
    } else if (i < 50176) {
        int j = i - 49152; int jo = j >> 5, k = j & 31;
        ws[i] = f2bf(ew2[k * 32 + jo]);
    }
}

// fused: out_h init copy + h->bf16 pack + x->float4 pack + out_x init copy
// ranges: [0,800000) h float4s; [800000,850000) xp nodes; [850000,887500) x float4 copy
__global__ void fused_init(const float4* __restrict__ h4,
                           const float* __restrict__ x,
                           const float4* __restrict__ x4,
                           float4* __restrict__ out4,
                           unsigned short* __restrict__ hb,
                           float4* __restrict__ xp) {
    int i = blockIdx.x * 256 + threadIdx.x;
    if (i < 800000) {
        float4 v = h4[i];
        out4[i] = v;
        if (hb) {
            uint2 u;
            u.x = pk2bf(v.x, v.y);
            u.y = pk2bf(v.z, v.w);
            *(uint2*)&hb[i * 4] = u;
        }
    } else if (i < 850000) {
        int n = i - 800000;
        if (xp) xp[n] = float4{x[n * 3], x[n * 3 + 1], x[n * 3 + 2], 0.f};
    } else if (i < 887500) {
        int j = i - 850000;
        out4[800000 + j] = x4[j];
    }
}

#define MIS 168   // m_input row stride (ushorts); 336B = 21*16B -> aligned + 2-way-free banks

// One wave per block, 32 edges per wave, zero barriers. LDS 10752 B -> ~15 blocks/CU.
__global__ __launch_bounds__(64, 4)
void egnn_edge_kernel(const float* __restrict__ h,
                      const unsigned short* __restrict__ hb,   // bf16 h copy (or null)
                      const float* __restrict__ x,
                      const float4* __restrict__ xp,           // packed x copy (or null)
                      const int* __restrict__ eidx,
                      const float* __restrict__ edist,
                      const float* __restrict__ node_b1,
                      const float* __restrict__ node_b2,
                      const float* __restrict__ coord_b1,
                      const float* __restrict__ coord_w2,
                      const float* __restrict__ ew1,
                      const float* __restrict__ eb1,
                      const float* __restrict__ eb2,
                      const unsigned short* __restrict__ ws,
                      float* __restrict__ out_h,
                      float* __restrict__ out_x) {
    __shared__ unsigned short mi[BE * MIS];   // 32*168*2 = 10752 B; m_input -> hidden tile

    const int l    = threadIdx.x;
    const int ln   = l & 15;
    const int quad = l >> 4;
    const int e0   = blockIdx.x * BE;

    // edge ids held in registers; lane e (0..31) owns edge e (dup'd in upper half)
    const int me   = l & 31;
    const int msrc = eidx[e0 + me];
    const int mdst = eidx[NE + e0 + me];

    // ---- stage cols 128..159: t[e][k] = silu(d*ew1[k]+eb1[k]) ----
    // lane l covers e = l>>1, k-range (l&1)*16..+16  (all 32 rows, own wave)
    {
        const int e = l >> 1, half = l & 1;
        const float d = edist[e0 + e];
        float t[16];
        #pragma unroll
        for (int j = 0; j < 16; ++j) {
            int k = half * 16 + j;
            t[j] = silu_f(d * ew1[k] + eb1[k]);
        }
        uint4 u0, u1;
        u0.x = pk2bf(t[0], t[1]);   u0.y = pk2bf(t[2], t[3]);
        u0.z = pk2bf(t[4], t[5]);   u0.w = pk2bf(t[6], t[7]);
        u1.x = pk2bf(t[8], t[9]);   u1.y = pk2bf(t[10], t[11]);
        u1.z = pk2bf(t[12], t[13]); u1.w = pk2bf(t[14], t[15]);
        *(uint4*)&mi[e * MIS + 128 + half * 16]     = u0;
        *(uint4*)&mi[e * MIS + 128 + half * 16 + 8] = u1;
    }

    // ---- stage cols 0..127: gather h[src] (cols 0..63), h[dst] (cols 64..127) ----
    // per iteration: 4 rows x 16 lanes; edge id pulled from registers via shfl
    if (hb) {
        const uint2* hb2 = (const uint2*)hb;
        #pragma unroll
        for (int it = 0; it < 16; ++it) {
            const int e = ((it & 7) << 2) + quad;                    // 0..31
            const int node = (it < 8) ? __shfl(msrc, e, 64) : __shfl(mdst, e, 64);
            const int cbase = (it < 8) ? 0 : 64;
            *(uint2*)&mi[e * MIS + cbase + ln * 4] = hb2[node * 16 + ln];
        }
    } else {
        const float4* h4 = (const float4*)h;
        #pragma unroll
        for (int it = 0; it < 16; ++it) {
            const int e = ((it & 7) << 2) + quad;
            const int node = (it < 8) ? __shfl(msrc, e, 64) : __shfl(mdst, e, 64);
            const int cbase = (it < 8) ? 0 : 64;
            float4 v = h4[node * 16 + ln];
            uint2 u;
            u.x = pk2bf(v.x, v.y);
            u.y = pk2bf(v.z, v.w);
            *(uint2*)&mi[e * MIS + cbase + ln * 4] = u;
        }
    }

    // NO barriers below: all LDS deps are same-wave; compiler orders via lgkmcnt.

    const int arow0 = ln * MIS;
    const int arow1 = (16 + ln) * MIS;
    const int koff  = quad * 8;
    const f32x4 zero = {0.f, 0.f, 0.f, 0.f};

    // ---- edge_attr = tmat @ ew2 + eb2 via MFMA, in place (cols 128..159) ----
    {
        const unsigned short* e2T = ws + WS_EW2T_US;
        short8 ta0 = *(const short8*)&mi[arow0 + 128 + koff];
        short8 ta1 = *(const short8*)&mi[arow1 + 128 + koff];
        f32x4 ea[2][2];
        ea[0][0] = zero; ea[0][1] = zero; ea[1][0] = zero; ea[1][1] = zero;
        #pragma unroll
        for (int nt = 0; nt < 2; ++nt) {
            short8 b = *(const short8*)(e2T + (nt * 16 + ln) * 32 + koff);
            ea[0][nt] = __builtin_amdgcn_mfma_f32_16x16x32_bf16(ta0, b, ea[0][nt], 0, 0, 0);
            ea[1][nt] = __builtin_amdgcn_mfma_f32_16x16x32_bf16(ta1, b, ea[1][nt], 0, 0, 0);
        }
        #pragma unroll
        for (int nt = 0; nt < 2; ++nt) {
            int col = nt * 16 + ln;
            float bv = eb2[col];
            #pragma unroll
            for (int rt = 0; rt < 2; ++rt) {
                #pragma unroll
                for (int r = 0; r < 4; ++r)
                    mi[(rt * 16 + quad * 4 + r) * MIS + 128 + col] =
                        f2bf(ea[rt][nt][r] + bv);
            }
        }
    }

    // ---- A fragments: load once, reuse for both GEMM1 phases ----
    short8 aA[5], aB[5];
    #pragma unroll
    for (int kc = 0; kc < 5; ++kc) {
        aA[kc] = *(const short8*)&mi[arow0 + kc * 32 + koff];
        aB[kc] = *(const short8*)&mi[arow1 + kc * 32 + koff];
    }

    const int wvoff = ln * 160 + koff;   // per-lane B-row offset (ushorts)

    // ---- GEMM1-coord: [32,160] @ [160,128], B straight from global (L1/L2-hot) ----
    f32x4 accC[2][8];
    #pragma unroll
    for (int a = 0; a < 2; ++a)
        #pragma unroll
        for (int b = 0; b < 8; ++b) accC[a][b] = zero;
    {
        const unsigned short* wsrc = ws + 20480;   // coord_w1^T
        #pragma unroll
        for (int half = 0; half < 2; ++half) {
            #pragma unroll
            for (int kc = 0; kc < 5; ++kc) {
                #pragma unroll
                for (int nt = 0; nt < 4; ++nt) {
                    short8 b = *(const short8*)(wsrc + half * 10240 + nt * 2560
                                                + kc * 32 + wvoff);
                    const int nn = half * 4 + nt;
                    accC[0][nn] = __builtin_amdgcn_mfma_f32_16x16x32_bf16(aA[kc], b, accC[0][nn], 0, 0, 0);
                    accC[1][nn] = __builtin_amdgcn_mfma_f32_16x16x32_bf16(aB[kc], b, accC[1][nn], 0, 0, 0);
                }
            }
        }
    }

    // ---- coord epilogue: cw[e] = silu(accC + b1c) . w2c, then x scatter ----
    {
        float cw[2][4];
        #pragma unroll
        for (int mt = 0; mt < 2; ++mt)
            #pragma unroll
            for (int r = 0; r < 4; ++r) cw[mt][r] = 0.f;
        #pragma unroll
        for (int nt = 0; nt < 8; ++nt) {
            int col = nt * 16 + ln;
            float b1v = coord_b1[col];
            float w2v = coord_w2[col];
            #pragma unroll
            for (int mt = 0; mt < 2; ++mt)
                #pragma unroll
                for (int r = 0; r < 4; ++r)
                    cw[mt][r] += silu_f(accC[mt][nt][r] + b1v) * w2v;
        }
        #pragma unroll
        for (int off = 1; off < 16; off <<= 1) {
            #pragma unroll
            for (int mt = 0; mt < 2; ++mt)
                #pragma unroll
                for (int r = 0; r < 4; ++r)
                    cw[mt][r] += __shfl_xor(cw[mt][r], off, 64);
        }
        // lanes ln<8 per quad each handle one (mt,r) edge; shuffles hoisted pre-branch
        const int smt = (ln >> 2) & 1, sr = ln & 3;
        const int lrow = (smt * 16 + quad * 4 + sr) & 31;
        const int s  = __shfl(msrc, lrow, 64);
        const int dn = __shfl(mdst, lrow, 64);
        if (ln < 8) {
            float cwsel = 0.f;
            #pragma unroll
            for (int mt = 0; mt < 2; ++mt)
                #pragma unroll
                for (int r = 0; r < 4; ++r)
                    cwsel = (mt == smt && r == sr) ? cw[mt][r] : cwsel;
            float dx, dy, dz;
            if (xp) {
                float4 xs = xp[s], xd = xp[dn];
                dx = xs.x - xd.x; dy = xs.y - xd.y; dz = xs.z - xd.z;
            } else {
                dx = x[s * 3]     - x[dn * 3];
                dy = x[s * 3 + 1] - x[dn * 3 + 1];
                dz = x[s * 3 + 2] - x[dn * 3 + 2];
            }
            float len = fmaxf(sqrtf(dx * dx + dy * dy + dz * dz), 1e-8f);
            float k = cwsel * __builtin_amdgcn_rcpf(len);
            atomicAdd(out_x + dn * 3,     k * dx);
            atomicAdd(out_x + dn * 3 + 1, k * dy);
            atomicAdd(out_x + dn * 3 + 2, k * dz);
        }
    }

    // ---- GEMM1-node ----
    f32x4 accN[2][8];
    #pragma unroll
    for (int a = 0; a < 2; ++a)
        #pragma unroll
        for (int b = 0; b < 8; ++b) accN[a][b] = zero;
    {
        const unsigned short* wsrc = ws;           // node_w1^T
        #pragma unroll
        for (int half = 0; half < 2; ++half) {
            #pragma unroll
            for (int kc = 0; kc < 5; ++kc) {
                #pragma unroll
                for (int nt = 0; nt < 4; ++nt) {
                    short8 b = *(const short8*)(wsrc + half * 10240 + nt * 2560
                                                + kc * 32 + wvoff);
                    const int nn = half * 4 + nt;
                    accN[0][nn] = __builtin_amdgcn_mfma_f32_16x16x32_bf16(aA[kc], b, accN[0][nn], 0, 0, 0);
                    accN[1][nn] = __builtin_amdgcn_mfma_f32_16x16x32_bf16(aB[kc], b, accN[1][nn], 0, 0, 0);
                }
            }
        }
    }

    // ---- hidden = silu(accN + b1) -> bf16, overwrite OWN rows of mi ----
    #pragma unroll
    for (int mt = 0; mt < 2; ++mt) {
        const int rowb = (mt * 16 + quad * 4) * MIS;
        #pragma unroll
        for (int nt = 0; nt < 8; ++nt) {
            int col = nt * 16 + ln;
            float b1v = node_b1[col];
            #pragma unroll
            for (int r = 0; r < 4; ++r)
                mi[rowb + r * MIS + col] = f2bf(silu_f(accN[mt][nt][r] + b1v));
        }
    }

    // ---- GEMM2-node: [32,128] @ [128,64] ----
    f32x4 acc2[2][4];
    #pragma unroll
    for (int a = 0; a < 2; ++a)
        #pragma unroll
        for (int b = 0; b < 4; ++b) acc2[a][b] = zero;
    const unsigned short* nw2T = ws + 40960;
    #pragma unroll
    for (int kc = 0; kc < 4; ++kc) {
        short8 a0 = *(const short8*)&mi[arow0 + kc * 32 + koff];
        short8 a1 = *(const short8*)&mi[arow1 + kc * 32 + koff];
        #pragma unroll
        for (int nt = 0; nt < 4; ++nt) {
            short8 b = *(const short8*)(nw2T + (nt * 16 + ln) * 128 + kc * 32 + koff);
            acc2[0][nt] = __builtin_amdgcn_mfma_f32_16x16x32_bf16(a0, b, acc2[0][nt], 0, 0, 0);
            acc2[1][nt] = __builtin_amdgcn_mfma_f32_16x16x32_bf16(a1, b, acc2[1][nt], 0, 0, 0);
        }
    }
    // ---- node scatter: out_h[dst] += m + b2 ----
    #pragma unroll
    for (int mt = 0; mt < 2; ++mt) {
        #pragma unroll
        for (int r = 0; r < 4; ++r) {
            int lrow = mt * 16 + quad * 4 + r;
            int dn = __shfl(mdst, lrow, 64);
            float* outrow = out_h + (size_t)dn * 64;
            #pragma unroll
            for (int nt = 0; nt < 4; ++nt) {
                int col = nt * 16 + ln;
                atomicAdd(outrow + col, acc2[mt][nt][r] + node_b2[col]);
            }
        }
    }
}

extern "C" void kernel_launch(void* const* d_in, const int* in_sizes, int n_in,
                              void* d_out, int out_size, void* d_ws, size_t ws_size,
                              hipStream_t stream) {
    const float* h    = (const float*)d_in[0];
    const float* x    = (const float*)d_in[1];
    const int*   eidx = (const int*)d_in[2];
    const float* edist= (const float*)d_in[3];
    const float* nw1  = (const float*)d_in[4];
    const float* nb1  = (const float*)d_in[5];
    const float* nw2  = (const float*)d_in[6];
    const float* nb2  = (const float*)d_in[7];
    const float* cw1  = (const float*)d_in[8];
    const float* cb1  = (const float*)d_in[9];
    const float* cw2  = (const float*)d_in[10];
    const float* ew1  = (const float*)d_in[11];
    const float* eb1  = (const float*)d_in[12];
    const float* ew2  = (const float*)d_in[13];
    const float* eb2  = (const float*)d_in[14];
    float* out = (float*)d_out;
    unsigned short* ws = (unsigned short*)d_ws;

    unsigned short* hb = nullptr;
    float4* xp = nullptr;
    if (ws_size >= (size_t)WS_HB_NEED) hb = (unsigned short*)((char*)d_ws + WS_HB_B);
    if (ws_size >= (size_t)WS_XP_NEED) xp = (float4*)((char*)d_ws + WS_XP_B);

    prep_kernel<<<196, 256, 0, stream>>>(nw1, cw1, nw2, ew2, ws);
    fused_init<<<3468, 256, 0, stream>>>((const float4*)h, x, (const float4*)x,
                                         (float4*)out, hb, xp);

    egnn_edge_kernel<<<NE / BE, 64, 0, stream>>>(h, hb, x, xp, eidx, edist,
                                                 nb1, nb2, cb1, cw2,
                                                 ew1, eb1, eb2,
                                                 ws, out, out + 3200000);
}